// Round 4
// baseline (153.586 us; speedup 1.0000x reference)
//
#include <hip/hip_runtime.h>
#include <hip/hip_bf16.h>

#define IN_F   1024
#define OUT_F  64
#define INTER  32
#define BATCH  512
#define NCOL   2048              // OUT_F * INTER
#define OUT_W  1088              // IN_F + OUT_F

typedef short bf16x8 __attribute__((ext_vector_type(8)));  // 8 bf16 (4 VGPRs)
typedef float f32x4  __attribute__((ext_vector_type(4)));  // 4 fp32 acc

__device__ __forceinline__ unsigned short f2bf(float v) {
    __hip_bfloat16 h = __float2bfloat16(v);
    return *reinterpret_cast<unsigned short*>(&h);
}

// ---------------- Prep: copy x -> out (+zero feature cols), cast x -> xb, transpose T -> Bt ----
__global__ __launch_bounds__(256) void prep_kernel(const float* __restrict__ x,
                                                   const float* __restrict__ T,
                                                   float* __restrict__ out,
                                                   unsigned short* __restrict__ xb,
                                                   unsigned short* __restrict__ Bt) {
    const int tid = threadIdx.x;
    if (blockIdx.x < BATCH) {
        const int r = blockIdx.x;
        const float4 v = ((const float4*)(x + (size_t)r * IN_F))[tid];
        *(float4*)(out + (size_t)r * OUT_W + tid * 4) = v;
        unsigned short h[4] = {f2bf(v.x), f2bf(v.y), f2bf(v.z), f2bf(v.w)};
        *(uint2*)(xb + (size_t)r * IN_F + tid * 4) = *(uint2*)h;
        if (tid < OUT_F / 4)   // zero-init minibatch-feature cols (pairwise atomically accumulates)
            *(float4*)(out + (size_t)r * OUT_W + IN_F + tid * 4) = make_float4(0.f, 0.f, 0.f, 0.f);
    } else {
        __shared__ unsigned short ldsT[64][72];   // [n][k], row stride 144B (16B-aligned)
        const int bid = blockIdx.x - BATCH;
        const int n0 = (bid & 31) * 64;
        const int k0 = (bid >> 5) * 64;
        const int nl = tid & 63;
        const int kc = (tid >> 6) * 16;
        unsigned short u[16];
        #pragma unroll
        for (int j = 0; j < 16; ++j)
            u[j] = f2bf(T[(size_t)(k0 + kc + j) * NCOL + n0 + nl]);
        *(uint4*)&ldsT[nl][kc]     = *(uint4*)&u[0];
        *(uint4*)&ldsT[nl][kc + 8] = *(uint4*)&u[8];
        __syncthreads();
        const int n2  = tid >> 2;
        const int kc2 = (tid & 3) * 16;
        uint4 a = *(uint4*)&ldsT[n2][kc2];
        uint4 b = *(uint4*)&ldsT[n2][kc2 + 8];
        unsigned short* dst = Bt + (size_t)(n0 + n2) * IN_F + k0 + kc2;
        *(uint4*)dst       = a;
        *(uint4*)(dst + 8) = b;
    }
}

// ---------------- GEMM (bf16 MFMA, no LDS, no barriers) ----------------
__global__ __launch_bounds__(256) void gemm_kernel(const unsigned short* __restrict__ xb,
                                                   const unsigned short* __restrict__ Bt,
                                                   float* __restrict__ Mt) {
    const int tid  = threadIdx.x;
    const int wave = tid >> 6, lane = tid & 63;
    const int quad = lane >> 4, lr = lane & 15;
    const int m0 = (blockIdx.y * 4 + wave) * 16;
    const int n0 = blockIdx.x * 32;

    const unsigned short* pA  = xb + (size_t)(m0 + lr) * IN_F + quad * 8;
    const unsigned short* pB0 = Bt + (size_t)(n0 + lr) * IN_F + quad * 8;
    const unsigned short* pB1 = pB0 + 16 * IN_F;

    f32x4 acc0 = {0.f, 0.f, 0.f, 0.f};
    f32x4 acc1 = {0.f, 0.f, 0.f, 0.f};
    #pragma unroll 8
    for (int k0 = 0; k0 < IN_F; k0 += 32) {
        bf16x8 a  = *(const bf16x8*)(pA + k0);
        bf16x8 b0 = *(const bf16x8*)(pB0 + k0);
        bf16x8 b1 = *(const bf16x8*)(pB1 + k0);
        acc0 = __builtin_amdgcn_mfma_f32_16x16x32_bf16(a, b0, acc0, 0, 0, 0);
        acc1 = __builtin_amdgcn_mfma_f32_16x16x32_bf16(a, b1, acc1, 0, 0, 0);
    }
    // C/D: col = lane&15, row = quad*4 + r. Output Mt[o][b][k].
    float* base = Mt + (size_t)(n0 >> 5) * (BATCH * INTER) + (size_t)(m0 + quad * 4) * INTER;
    #pragma unroll
    for (int r = 0; r < 4; ++r) {
        base[r * INTER + lr]      = acc0[r];
        base[r * INTER + 16 + lr] = acc1[r];
    }
}

// ---------------- Pairwise L1 + exp, b-sliced for occupancy ----------------
// grid (8 a-chunks, 64 o, 4 b-slices), block 256 (4 waves); wave w covers 32 b's.
// 2048 blocks -> 7 waves/SIMD at VGPR=68 (vs 2 before). One atomicAdd per (a,o) per block.
__global__ __launch_bounds__(256) void pairwise_kernel(const float* __restrict__ Mt,
                                                       float* __restrict__ out) {
    const int o    = blockIdx.y;
    const int a0   = blockIdx.x * 64;
    const int bs   = blockIdx.z;
    const int lane = threadIdx.x & 63;
    const int wave = threadIdx.x >> 6;
    const int a    = a0 + lane;
    const float* slab = Mt + (size_t)o * (BATCH * INTER);

    float ma[INTER];
    {
        const float* pa = slab + (size_t)a * INTER;
        #pragma unroll
        for (int k = 0; k < INTER; k += 4) {
            const float4 v = *(const float4*)(pa + k);
            ma[k] = v.x; ma[k + 1] = v.y; ma[k + 2] = v.z; ma[k + 3] = v.w;
        }
    }

    float f = 0.f;
    const float* pb = slab + (size_t)((bs * 4 + wave) * 32) * INTER;
    #pragma unroll 2
    for (int b = 0; b < 32; ++b) {
        float d0 = 0.f, d1 = 0.f, d2 = 0.f, d3 = 0.f;  // 4 accs break dep chain
        #pragma unroll
        for (int k = 0; k < INTER; k += 4) {
            const float4 mb = *(const float4*)(pb + k);   // wave-uniform
            d0 += fabsf(ma[k]     - mb.x);
            d1 += fabsf(ma[k + 1] - mb.y);
            d2 += fabsf(ma[k + 2] - mb.z);
            d3 += fabsf(ma[k + 3] - mb.w);
        }
        f += __expf(-((d0 + d1) + (d2 + d3)));
        pb += INTER;
    }

    __shared__ float part[4][64];
    part[wave][lane] = f;
    __syncthreads();
    if (wave == 0) {
        const float s = part[0][lane] + part[1][lane] + part[2][lane] + part[3][lane];
        atomicAdd(&out[(size_t)a * OUT_W + IN_F + o], s);
    }
}

extern "C" void kernel_launch(void* const* d_in, const int* in_sizes, int n_in,
                              void* d_out, int out_size, void* d_ws, size_t ws_size,
                              hipStream_t stream) {
    const float* x = (const float*)d_in[0];   // [512,1024] fp32
    const float* T = (const float*)d_in[1];   // [1024,2048] fp32 row-major (k-major)
    float* out = (float*)d_out;               // [512,1088] fp32

    // ws layout: xb (1MB) | Bt (4MB) | Mt (4MB) = 9MB
    unsigned short* xb = (unsigned short*)d_ws;                          // [512][1024] bf16
    unsigned short* Bt = (unsigned short*)((char*)d_ws + (1u << 20));    // [2048][1024] bf16
    float*          Mt = (float*)((char*)d_ws + (5u << 20));             // [64][512][32] fp32

    prep_kernel<<<1024, 256, 0, stream>>>(x, T, out, xb, Bt);

    dim3 ggrid(NCOL / 32, BATCH / 64);        // 64 x 8 = 512 blocks
    gemm_kernel<<<ggrid, 256, 0, stream>>>(xb, Bt, Mt);

    dim3 pgrid(BATCH / 64, OUT_F, 4);         // 2048 blocks
    pairwise_kernel<<<pgrid, 256, 0, stream>>>(Mt, out);
}

// Round 5
// 137.574 us; speedup vs baseline: 1.1164x; 1.1164x over previous
//
#include <hip/hip_runtime.h>
#include <hip/hip_bf16.h>

#define IN_F   1024
#define OUT_F  64
#define INTER  32
#define BATCH  512
#define NCOL   2048              // OUT_F * INTER
#define OUT_W  1088              // IN_F + OUT_F

typedef short bf16x8 __attribute__((ext_vector_type(8)));  // 8 bf16 (4 VGPRs)
typedef float f32x4  __attribute__((ext_vector_type(4)));  // 4 fp32 acc

__device__ __forceinline__ unsigned short f2bf(float v) {
    __hip_bfloat16 h = __float2bfloat16(v);
    return *reinterpret_cast<unsigned short*>(&h);
}

// ---------------- Prep: copy x -> out (+zero feature cols), cast x -> xb, transpose T -> Bt ----
__global__ __launch_bounds__(256) void prep_kernel(const float* __restrict__ x,
                                                   const float* __restrict__ T,
                                                   float* __restrict__ out,
                                                   unsigned short* __restrict__ xb,
                                                   unsigned short* __restrict__ Bt) {
    const int tid = threadIdx.x;
    if (blockIdx.x < BATCH) {
        const int r = blockIdx.x;
        const float4 v = ((const float4*)(x + (size_t)r * IN_F))[tid];
        *(float4*)(out + (size_t)r * OUT_W + tid * 4) = v;
        unsigned short h[4] = {f2bf(v.x), f2bf(v.y), f2bf(v.z), f2bf(v.w)};
        *(uint2*)(xb + (size_t)r * IN_F + tid * 4) = *(uint2*)h;
        if (tid < OUT_F / 4)   // zero-init minibatch-feature cols (pairwise accumulates atomically)
            *(float4*)(out + (size_t)r * OUT_W + IN_F + tid * 4) = make_float4(0.f, 0.f, 0.f, 0.f);
    } else {
        __shared__ unsigned short ldsT[64][72];   // [n][k], row stride 144B (16B-aligned)
        const int bid = blockIdx.x - BATCH;
        const int n0 = (bid & 31) * 64;
        const int k0 = (bid >> 5) * 64;
        const int nl = tid & 63;
        const int kc = (tid >> 6) * 16;
        unsigned short u[16];
        #pragma unroll
        for (int j = 0; j < 16; ++j)
            u[j] = f2bf(T[(size_t)(k0 + kc + j) * NCOL + n0 + nl]);
        *(uint4*)&ldsT[nl][kc]     = *(uint4*)&u[0];
        *(uint4*)&ldsT[nl][kc + 8] = *(uint4*)&u[8];
        __syncthreads();
        const int n2  = tid >> 2;
        const int kc2 = (tid & 3) * 16;
        uint4 a = *(uint4*)&ldsT[n2][kc2];
        uint4 b = *(uint4*)&ldsT[n2][kc2 + 8];
        unsigned short* dst = Bt + (size_t)(n0 + n2) * IN_F + k0 + kc2;
        *(uint4*)dst       = a;
        *(uint4*)(dst + 8) = b;
    }
}

// ---------------- GEMM (bf16 MFMA, no LDS, no barriers) ----------------
__global__ __launch_bounds__(256) void gemm_kernel(const unsigned short* __restrict__ xb,
                                                   const unsigned short* __restrict__ Bt,
                                                   float* __restrict__ Mt) {
    const int tid  = threadIdx.x;
    const int wave = tid >> 6, lane = tid & 63;
    const int quad = lane >> 4, lr = lane & 15;
    const int m0 = (blockIdx.y * 4 + wave) * 16;
    const int n0 = blockIdx.x * 32;

    const unsigned short* pA  = xb + (size_t)(m0 + lr) * IN_F + quad * 8;
    const unsigned short* pB0 = Bt + (size_t)(n0 + lr) * IN_F + quad * 8;
    const unsigned short* pB1 = pB0 + 16 * IN_F;

    f32x4 acc0 = {0.f, 0.f, 0.f, 0.f};
    f32x4 acc1 = {0.f, 0.f, 0.f, 0.f};
    #pragma unroll 8
    for (int k0 = 0; k0 < IN_F; k0 += 32) {
        bf16x8 a  = *(const bf16x8*)(pA + k0);
        bf16x8 b0 = *(const bf16x8*)(pB0 + k0);
        bf16x8 b1 = *(const bf16x8*)(pB1 + k0);
        acc0 = __builtin_amdgcn_mfma_f32_16x16x32_bf16(a, b0, acc0, 0, 0, 0);
        acc1 = __builtin_amdgcn_mfma_f32_16x16x32_bf16(a, b1, acc1, 0, 0, 0);
    }
    // C/D: col = lane&15, row = quad*4 + r. Output Mt[o][b][k].
    float* base = Mt + (size_t)(n0 >> 5) * (BATCH * INTER) + (size_t)(m0 + quad * 4) * INTER;
    #pragma unroll
    for (int r = 0; r < 4; ++r) {
        base[r * INTER + lr]      = acc0[r];
        base[r * INTER + 16 + lr] = acc1[r];
    }
}

// ---------------- Pairwise L1 + exp: 4 a-rows per lane (amortize VMEM over 4x VALU) ----------------
// grid (2 a-chunks, 64 o, 4 b-slices), block 256 (4 waves). Lane holds ma for a = ac*256 + r*64 + lane,
// r=0..3 (128 VGPRs). Wave w covers b in [bs*128 + w*32, +32). VMEM wave-instrs: 2.1M -> 0.59M.
__global__ __launch_bounds__(256) void pairwise_kernel(const float* __restrict__ Mt,
                                                       float* __restrict__ out) {
    const int o    = blockIdx.y;
    const int ac   = blockIdx.x;         // 0..1
    const int bs   = blockIdx.z;         // 0..3
    const int lane = threadIdx.x & 63;
    const int wave = threadIdx.x >> 6;
    const float* slab = Mt + (size_t)o * (BATCH * INTER);

    float ma[4][INTER];
    #pragma unroll
    for (int r = 0; r < 4; ++r) {
        const float* pa = slab + (size_t)(ac * 256 + r * 64 + lane) * INTER;
        #pragma unroll
        for (int k = 0; k < INTER; k += 4) {
            const float4 v = *(const float4*)(pa + k);
            ma[r][k] = v.x; ma[r][k + 1] = v.y; ma[r][k + 2] = v.z; ma[r][k + 3] = v.w;
        }
    }

    float f[4] = {0.f, 0.f, 0.f, 0.f};
    const float* pb = slab + (size_t)(bs * 128 + wave * 32) * INTER;
    #pragma unroll 2
    for (int b = 0; b < 32; ++b) {
        float d0[4] = {0.f, 0.f, 0.f, 0.f};
        float d1[4] = {0.f, 0.f, 0.f, 0.f};   // 2 chains x 4 rows = 8 independent accums
        #pragma unroll
        for (int k = 0; k < INTER; k += 4) {
            const float4 mb = *(const float4*)(pb + k);   // wave-uniform
            #pragma unroll
            for (int r = 0; r < 4; ++r) {
                d0[r] += fabsf(ma[r][k]     - mb.x);
                d1[r] += fabsf(ma[r][k + 1] - mb.y);
                d0[r] += fabsf(ma[r][k + 2] - mb.z);
                d1[r] += fabsf(ma[r][k + 3] - mb.w);
            }
        }
        #pragma unroll
        for (int r = 0; r < 4; ++r)
            f[r] += __expf(-(d0[r] + d1[r]));
        pb += INTER;
    }

    __shared__ float part[4][4][64];     // [wave][r][lane], 4 KB
    #pragma unroll
    for (int r = 0; r < 4; ++r)
        part[wave][r][lane] = f[r];
    __syncthreads();
    if (wave == 0) {
        #pragma unroll
        for (int r = 0; r < 4; ++r) {
            const float s = part[0][r][lane] + part[1][r][lane]
                          + part[2][r][lane] + part[3][r][lane];
            atomicAdd(&out[(size_t)(ac * 256 + r * 64 + lane) * OUT_W + IN_F + o], s);
        }
    }
}

extern "C" void kernel_launch(void* const* d_in, const int* in_sizes, int n_in,
                              void* d_out, int out_size, void* d_ws, size_t ws_size,
                              hipStream_t stream) {
    const float* x = (const float*)d_in[0];   // [512,1024] fp32
    const float* T = (const float*)d_in[1];   // [1024,2048] fp32 row-major (k-major)
    float* out = (float*)d_out;               // [512,1088] fp32

    // ws layout: xb (1MB) | Bt (4MB) | Mt (4MB) = 9MB
    unsigned short* xb = (unsigned short*)d_ws;                          // [512][1024] bf16
    unsigned short* Bt = (unsigned short*)((char*)d_ws + (1u << 20));    // [2048][1024] bf16
    float*          Mt = (float*)((char*)d_ws + (5u << 20));             // [64][512][32] fp32

    prep_kernel<<<1024, 256, 0, stream>>>(x, T, out, xb, Bt);

    dim3 ggrid(NCOL / 32, BATCH / 64);        // 64 x 8 = 512 blocks
    gemm_kernel<<<ggrid, 256, 0, stream>>>(xb, Bt, Mt);

    dim3 pgrid(2, OUT_F, 4);                  // 512 blocks, 2/CU
    pairwise_kernel<<<pgrid, 256, 0, stream>>>(Mt, out);
}

// Round 6
// 128.533 us; speedup vs baseline: 1.1949x; 1.0703x over previous
//
#include <hip/hip_runtime.h>
#include <hip/hip_bf16.h>

#define IN_F   1024
#define OUT_F  64
#define INTER  32
#define BATCH  512
#define NCOL   2048              // OUT_F * INTER
#define OUT_W  1088              // IN_F + OUT_F

typedef short bf16x8 __attribute__((ext_vector_type(8)));  // 8 bf16 (4 VGPRs)
typedef float f32x4  __attribute__((ext_vector_type(4)));  // 4 fp32 acc

__device__ __forceinline__ unsigned short f2bf(float v) {
    __hip_bfloat16 h = __float2bfloat16(v);
    return *reinterpret_cast<unsigned short*>(&h);
}

// ---------------- Prep: copy x -> out (+zero feature cols), cast x -> xb, transpose T -> Bt ----
__global__ __launch_bounds__(256) void prep_kernel(const float* __restrict__ x,
                                                   const float* __restrict__ T,
                                                   float* __restrict__ out,
                                                   unsigned short* __restrict__ xb,
                                                   unsigned short* __restrict__ Bt) {
    const int tid = threadIdx.x;
    if (blockIdx.x < BATCH) {
        const int r = blockIdx.x;
        const float4 v = ((const float4*)(x + (size_t)r * IN_F))[tid];
        *(float4*)(out + (size_t)r * OUT_W + tid * 4) = v;
        unsigned short h[4] = {f2bf(v.x), f2bf(v.y), f2bf(v.z), f2bf(v.w)};
        *(uint2*)(xb + (size_t)r * IN_F + tid * 4) = *(uint2*)h;
        if (tid < OUT_F / 4)   // zero-init minibatch-feature cols (pairwise accumulates atomically)
            *(float4*)(out + (size_t)r * OUT_W + IN_F + tid * 4) = make_float4(0.f, 0.f, 0.f, 0.f);
    } else {
        __shared__ unsigned short ldsT[64][72];   // [n][k], row stride 144B (16B-aligned)
        const int bid = blockIdx.x - BATCH;
        const int n0 = (bid & 31) * 64;
        const int k0 = (bid >> 5) * 64;
        const int nl = tid & 63;
        const int kc = (tid >> 6) * 16;
        unsigned short u[16];
        #pragma unroll
        for (int j = 0; j < 16; ++j)
            u[j] = f2bf(T[(size_t)(k0 + kc + j) * NCOL + n0 + nl]);
        *(uint4*)&ldsT[nl][kc]     = *(uint4*)&u[0];
        *(uint4*)&ldsT[nl][kc + 8] = *(uint4*)&u[8];
        __syncthreads();
        const int n2  = tid >> 2;
        const int kc2 = (tid & 3) * 16;
        uint4 a = *(uint4*)&ldsT[n2][kc2];
        uint4 b = *(uint4*)&ldsT[n2][kc2 + 8];
        unsigned short* dst = Bt + (size_t)(n0 + n2) * IN_F + k0 + kc2;
        *(uint4*)dst       = a;
        *(uint4*)(dst + 8) = b;
    }
}

// ---------------- GEMM (bf16 MFMA, no LDS, no barriers) ----------------
__global__ __launch_bounds__(256) void gemm_kernel(const unsigned short* __restrict__ xb,
                                                   const unsigned short* __restrict__ Bt,
                                                   float* __restrict__ Mt) {
    const int tid  = threadIdx.x;
    const int wave = tid >> 6, lane = tid & 63;
    const int quad = lane >> 4, lr = lane & 15;
    const int m0 = (blockIdx.y * 4 + wave) * 16;
    const int n0 = blockIdx.x * 32;

    const unsigned short* pA  = xb + (size_t)(m0 + lr) * IN_F + quad * 8;
    const unsigned short* pB0 = Bt + (size_t)(n0 + lr) * IN_F + quad * 8;
    const unsigned short* pB1 = pB0 + 16 * IN_F;

    f32x4 acc0 = {0.f, 0.f, 0.f, 0.f};
    f32x4 acc1 = {0.f, 0.f, 0.f, 0.f};
    #pragma unroll 8
    for (int k0 = 0; k0 < IN_F; k0 += 32) {
        bf16x8 a  = *(const bf16x8*)(pA + k0);
        bf16x8 b0 = *(const bf16x8*)(pB0 + k0);
        bf16x8 b1 = *(const bf16x8*)(pB1 + k0);
        acc0 = __builtin_amdgcn_mfma_f32_16x16x32_bf16(a, b0, acc0, 0, 0, 0);
        acc1 = __builtin_amdgcn_mfma_f32_16x16x32_bf16(a, b1, acc1, 0, 0, 0);
    }
    // C/D: col = lane&15, row = quad*4 + r. Output Mt[o][b][k].
    float* base = Mt + (size_t)(n0 >> 5) * (BATCH * INTER) + (size_t)(m0 + quad * 4) * INTER;
    #pragma unroll
    for (int r = 0; r < 4; ++r) {
        base[r * INTER + lr]      = acc0[r];
        base[r * INTER + 16 + lr] = acc1[r];
    }
}

// ---------------- Pairwise L1 + exp: 4 a-rows/lane in VGPRs, mb via LDS broadcast ----------------
// grid (2 a-chunks, 64 o, 4 b-slices), block 256 (4 waves).
// __launch_bounds__(256,2): 256-VGPR budget so ma[4][32] (128 VGPRs) stays register-resident
// (R5's plain (256) gave VGPR=92 -> ma spilled, defeating the reuse).
// Block stages its 128 mb-rows (16 KB) into LDS once; inner loop reads mb with wave-uniform
// ds_read_b128 (broadcast, no bank conflicts, zero VMEM/TA cost).
__global__ __launch_bounds__(256, 2) void pairwise_kernel(const float* __restrict__ Mt,
                                                          float* __restrict__ out) {
    const int o    = blockIdx.y;
    const int ac   = blockIdx.x;         // 0..1
    const int bs   = blockIdx.z;         // 0..3
    const int tid  = threadIdx.x;
    const int lane = tid & 63;
    const int wave = tid >> 6;
    const float* slab = Mt + (size_t)o * (BATCH * INTER);

    __shared__ float mb_lds[128 * INTER];   // 16 KB: rows [bs*128, bs*128+128)
    {
        const float4* src = (const float4*)(slab + (size_t)bs * 128 * INTER);
        float4* dst = (float4*)mb_lds;
        #pragma unroll
        for (int i = 0; i < 4; ++i)
            dst[tid + 256 * i] = src[tid + 256 * i];
    }

    float ma[4][INTER];                     // 128 VGPRs; overlaps staging latency
    #pragma unroll
    for (int r = 0; r < 4; ++r) {
        const float* pa = slab + (size_t)(ac * 256 + r * 64 + lane) * INTER;
        #pragma unroll
        for (int k = 0; k < INTER; k += 4) {
            const float4 v = *(const float4*)(pa + k);
            ma[r][k] = v.x; ma[r][k + 1] = v.y; ma[r][k + 2] = v.z; ma[r][k + 3] = v.w;
        }
    }
    __syncthreads();

    float f[4] = {0.f, 0.f, 0.f, 0.f};
    const float* pb = mb_lds + wave * 32 * INTER;   // wave w covers 32 local b-rows
    #pragma unroll 2
    for (int b = 0; b < 32; ++b) {
        float d0[4] = {0.f, 0.f, 0.f, 0.f};
        float d1[4] = {0.f, 0.f, 0.f, 0.f};   // 8 independent accum chains
        #pragma unroll
        for (int k = 0; k < INTER; k += 4) {
            const float4 mb = *(const float4*)(pb + k);   // ds_read_b128, wave-uniform
            #pragma unroll
            for (int r = 0; r < 4; ++r) {
                d0[r] += fabsf(ma[r][k]     - mb.x);
                d1[r] += fabsf(ma[r][k + 1] - mb.y);
                d0[r] += fabsf(ma[r][k + 2] - mb.z);
                d1[r] += fabsf(ma[r][k + 3] - mb.w);
            }
        }
        #pragma unroll
        for (int r = 0; r < 4; ++r)
            f[r] += __expf(-(d0[r] + d1[r]));
        pb += INTER;
    }

    __shared__ float part[4][4][64];     // [wave][r][lane], 4 KB
    #pragma unroll
    for (int r = 0; r < 4; ++r)
        part[wave][r][lane] = f[r];
    __syncthreads();
    if (wave == 0) {
        #pragma unroll
        for (int r = 0; r < 4; ++r) {
            const float s = part[0][r][lane] + part[1][r][lane]
                          + part[2][r][lane] + part[3][r][lane];
            atomicAdd(&out[(size_t)(ac * 256 + r * 64 + lane) * OUT_W + IN_F + o], s);
        }
    }
}

extern "C" void kernel_launch(void* const* d_in, const int* in_sizes, int n_in,
                              void* d_out, int out_size, void* d_ws, size_t ws_size,
                              hipStream_t stream) {
    const float* x = (const float*)d_in[0];   // [512,1024] fp32
    const float* T = (const float*)d_in[1];   // [1024,2048] fp32 row-major (k-major)
    float* out = (float*)d_out;               // [512,1088] fp32

    // ws layout: xb (1MB) | Bt (4MB) | Mt (4MB) = 9MB
    unsigned short* xb = (unsigned short*)d_ws;                          // [512][1024] bf16
    unsigned short* Bt = (unsigned short*)((char*)d_ws + (1u << 20));    // [2048][1024] bf16
    float*          Mt = (float*)((char*)d_ws + (5u << 20));             // [64][512][32] fp32

    prep_kernel<<<1024, 256, 0, stream>>>(x, T, out, xb, Bt);

    dim3 ggrid(NCOL / 32, BATCH / 64);        // 64 x 8 = 512 blocks
    gemm_kernel<<<ggrid, 256, 0, stream>>>(xb, Bt, Mt);

    dim3 pgrid(2, OUT_F, 4);                  // 512 blocks, 2/CU
    pairwise_kernel<<<pgrid, 256, 0, stream>>>(Mt, out);
}